// Round 2
// baseline (555.992 us; speedup 1.0000x reference)
//
#include <hip/hip_runtime.h>
#include <hip/hip_bf16.h>

// Problem constants (from reference): B=8, S=1024, E=64, H=8, DK=8
#define BB 8
#define SS 1024
#define EE 64
#define HH 8
#define DKW 8

typedef __hip_bfloat16 bf16;
typedef unsigned short u16;

// d_ws layout:
//   [0, 4)        int flag: 1 = inputs/outputs are float32, 0 = bf16
//   [256, 256+2MB) float proj[B*S*E]

// ---------------------------------------------------------------------------
// Detect input dtype. If the underlying data is float32, the low 16 bits of
// each 32-bit word are random mantissa bits -> ~48% decode (as bf16) to
// |v| >= 32. If the data is genuine bf16 ~ N(0,1), essentially none do.
__global__ __launch_bounds__(256) void detect_kernel(const u16* __restrict__ xr,
                                                     int* __restrict__ flag) {
    __shared__ int red[4];
    int tid = threadIdx.x;
    int cnt = 0;
#pragma unroll
    for (int i = 0; i < 8; ++i) {
        u16 u = xr[(tid * 8 + i) * 2];   // even u16 index = low half of word i
        int ex = (u >> 7) & 0xFF;        // bf16 exponent field
        if (ex >= 0x84) cnt++;           // |bf16| >= 32
    }
#pragma unroll
    for (int off = 32; off > 0; off >>= 1) cnt += __shfl_xor(cnt, off, 64);
    if ((tid & 63) == 0) red[tid >> 6] = cnt;
    __syncthreads();
    if (tid == 0) flag[0] = ((red[0] + red[1] + red[2] + red[3]) > 64) ? 1 : 0;
}

// ---------------------------------------------------------------------------
// Analytic quantum projection. The RX-product state has independent bits with
// E[(-1)^{b_j}] = cos(theta_j); the CNOT ring is a basis permutation:
//   a_w = b_0^...^b_w (w>=1), a_0 = b_1^...^b_7
// => Z_0 = prod_{j=1..7} cos(theta_j);  Z_w = prod_{j=0..w} cos(theta_j)
__global__ __launch_bounds__(256) void proj_kernel(const void* __restrict__ x,
                                                   const void* __restrict__ phi,
                                                   const int* __restrict__ flag,
                                                   float* __restrict__ proj) {
    int m = blockIdx.x * blockDim.x + threadIdx.x;  // 0 .. B*S*H-1
    int h = m & (HH - 1);
    bool f32 = (flag[0] != 0);

    float th[DKW];
    if (f32) {
        const float4* xp = (const float4*)((const float*)x + (size_t)m * DKW);
        const float4* pp = (const float4*)((const float*)phi + h * DKW);
        float4 x0 = xp[0], x1 = xp[1];
        float4 p0 = pp[0], p1 = pp[1];
        th[0] = x0.x + p0.x; th[1] = x0.y + p0.y; th[2] = x0.z + p0.z; th[3] = x0.w + p0.w;
        th[4] = x1.x + p1.x; th[5] = x1.y + p1.y; th[6] = x1.z + p1.z; th[7] = x1.w + p1.w;
    } else {
        union { uint4 u; bf16 hv[8]; } xu, pu;
        xu.u = *(const uint4*)((const bf16*)x + (size_t)m * DKW);
        pu.u = *(const uint4*)((const bf16*)phi + (size_t)h * DKW);
#pragma unroll
        for (int j = 0; j < DKW; ++j)
            th[j] = __bfloat162float(xu.hv[j]) + __bfloat162float(pu.hv[j]);
    }

    float c[DKW];
#pragma unroll
    for (int j = 0; j < DKW; ++j) c[j] = __cosf(th[j]);

    float z[DKW];
    float suf = c[1];
#pragma unroll
    for (int j = 2; j < DKW; ++j) suf *= c[j];
    z[0] = suf;                       // Z_0 = c1*...*c7
    float pre = c[0];
#pragma unroll
    for (int w = 1; w < DKW; ++w) { pre *= c[w]; z[w] = pre; }  // Z_w = c0*...*cw

    float4* o = (float4*)(proj + (size_t)m * DKW);
    o[0] = make_float4(z[0], z[1], z[2], z[3]);
    o[1] = make_float4(z[4], z[5], z[6], z[7]);
}

// ---------------------------------------------------------------------------
// One block (256 threads = 4 waves) per (b, s) query row.
// scores = softmax(q . K^T / sqrt(8)); ctx = scores @ P; out = W @ ctx + bias
__global__ __launch_bounds__(256) void attn_kernel(const float* __restrict__ proj,
                                                   const void* __restrict__ Wp,
                                                   const void* __restrict__ biasp,
                                                   const int* __restrict__ flag,
                                                   void* __restrict__ outp) {
    const int b = blockIdx.y;
    const int s = blockIdx.x;
    const int tid = threadIdx.x;
    const bool f32 = (flag[0] != 0);

    __shared__ float q[EE];
    __shared__ float p[SS];
    __shared__ float red[8];
    __shared__ float part[4][EE];
    __shared__ float ctx[EE];

    const float* Pb = proj + (size_t)b * SS * EE;

    if (tid < EE) q[tid] = Pb[(size_t)s * EE + tid];
    __syncthreads();

    const float scale = 0.35355339059327373f;  // 1/sqrt(DK)
    float sc[4];
    float mloc = -1e30f;
    const float4* qv = (const float4*)q;
#pragma unroll
    for (int k = 0; k < 4; ++k) {
        int t = tid + k * 256;
        const float4* row = (const float4*)(Pb + (size_t)t * EE);
        float dot = 0.f;
#pragma unroll
        for (int i = 0; i < 16; ++i) {
            float4 r = row[i];
            float4 qq = qv[i];
            dot += r.x * qq.x + r.y * qq.y + r.z * qq.z + r.w * qq.w;
        }
        sc[k] = dot * scale;
        mloc = fmaxf(mloc, sc[k]);
    }

#pragma unroll
    for (int off = 32; off > 0; off >>= 1)
        mloc = fmaxf(mloc, __shfl_xor(mloc, off, 64));
    int wave = tid >> 6;
    if ((tid & 63) == 0) red[wave] = mloc;
    __syncthreads();
    float m = fmaxf(fmaxf(red[0], red[1]), fmaxf(red[2], red[3]));

    float lsum = 0.f;
#pragma unroll
    for (int k = 0; k < 4; ++k) {
        float e = __expf(sc[k] - m);
        p[tid + k * 256] = e;
        lsum += e;
    }
#pragma unroll
    for (int off = 32; off > 0; off >>= 1)
        lsum += __shfl_xor(lsum, off, 64);
    if ((tid & 63) == 0) red[4 + wave] = lsum;
    __syncthreads();
    float sumv = red[4] + red[5] + red[6] + red[7];

    // PV: lane = output channel e, wave = chunk of 256 keys (coalesced)
    int e_idx = tid & 63;
    int chunk = tid >> 6;
    float acc = 0.f;
    int t0 = chunk * 256;
    for (int t = t0; t < t0 + 256; ++t)
        acc += p[t] * Pb[(size_t)t * EE + e_idx];
    part[chunk][e_idx] = acc;
    __syncthreads();
    if (tid < EE)
        ctx[tid] = (part[0][tid] + part[1][tid] + part[2][tid] + part[3][tid]) / sumv;
    __syncthreads();

    // fused output linear: out[e] = bias[e] + sum_j W[e,j] * ctx[j]
    if (tid < EE) {
        float acc2;
        if (f32) {
            const float* wr = (const float*)Wp + (size_t)tid * EE;
            acc2 = ((const float*)biasp)[tid];
#pragma unroll
            for (int j = 0; j < EE; ++j) acc2 += wr[j] * ctx[j];
        } else {
            const bf16* wr = (const bf16*)Wp + (size_t)tid * EE;
            acc2 = __bfloat162float(((const bf16*)biasp)[tid]);
#pragma unroll
            for (int j = 0; j < EE; ++j) acc2 += __bfloat162float(wr[j]) * ctx[j];
        }
        size_t oi = ((size_t)(b * SS + s)) * EE + tid;
        if (f32) ((float*)outp)[oi] = acc2;
        else     ((bf16*)outp)[oi] = __float2bfloat16(acc2);
    }
}

extern "C" void kernel_launch(void* const* d_in, const int* in_sizes, int n_in,
                              void* d_out, int out_size, void* d_ws, size_t ws_size,
                              hipStream_t stream) {
    const void* x    = d_in[0];  // [B,S,E]
    const void* phi  = d_in[1];  // [H,DK]
    const void* W    = d_in[2];  // [E,E]
    const void* bias = d_in[3];  // [E]

    int*   flag = (int*)d_ws;
    float* proj = (float*)((char*)d_ws + 256);  // [B,S,E] fp32, 2 MB

    detect_kernel<<<dim3(1), dim3(256), 0, stream>>>((const u16*)x, flag);
    proj_kernel<<<dim3(BB * SS * HH / 256), dim3(256), 0, stream>>>(x, phi, flag, proj);
    dim3 g(SS, BB);
    attn_kernel<<<g, dim3(256), 0, stream>>>(proj, W, bias, flag, d_out);
}

// Round 3
// 107.645 us; speedup vs baseline: 5.1650x; 5.1650x over previous
//
#include <hip/hip_runtime.h>
#include <hip/hip_bf16.h>

// Problem constants (from reference): B=8, S=1024, E=64, H=8, DK=8
#define BB 8
#define SS 1024
#define EE 64
#define HH 8
#define DKW 8

typedef __hip_bfloat16 bf16;
typedef unsigned short u16;
typedef _Float16 half8v __attribute__((ext_vector_type(8)));
typedef float floatx4 __attribute__((ext_vector_type(4)));

#define MFMA16(a, b, c) __builtin_amdgcn_mfma_f32_16x16x32_f16(a, b, c, 0, 0, 0)

// ---------------------------------------------------------------------------
// d_ws layout (fast path):
//   [0,4)                 int flag: 1 = float32 inputs/outputs, 0 = bf16
//   [256, +1MB)           _Float16 projH[B][S][E]
//   [.., +1MB)            _Float16 projT[B][E][S]
//   [.., +16MB)           _Float16 S/P  [B][S][S]   (softmax done in place)
#define OFF_PROJH 256
#define OFF_PROJT (256 + BB*SS*EE*2)
#define OFF_SMAT  (256 + 2*BB*SS*EE*2)
#define WS_NEED_FAST ((size_t)OFF_SMAT + (size_t)BB*SS*SS*2)
#define WS_NEED_SLOW ((size_t)256 + (size_t)BB*SS*EE*4)

// ---------------------------------------------------------------------------
// Detect input dtype: if data is really float32, the low 16 bits of each
// 32-bit word are random mantissa bits -> ~48% decode (as bf16) to |v|>=32.
__global__ __launch_bounds__(256) void detect_kernel(const u16* __restrict__ xr,
                                                     int* __restrict__ flag) {
    __shared__ int red[4];
    int tid = threadIdx.x;
    int cnt = 0;
#pragma unroll
    for (int i = 0; i < 8; ++i) {
        u16 u = xr[(tid * 8 + i) * 2];
        int ex = (u >> 7) & 0xFF;
        if (ex >= 0x84) cnt++;
    }
#pragma unroll
    for (int off = 32; off > 0; off >>= 1) cnt += __shfl_xor(cnt, off, 64);
    if ((tid & 63) == 0) red[tid >> 6] = cnt;
    __syncthreads();
    if (tid == 0) flag[0] = ((red[0] + red[1] + red[2] + red[3]) > 64) ? 1 : 0;
}

// ---------------------------------------------------------------------------
// Analytic quantum projection (see R0 derivation):
//   Z_0 = prod_{j=1..7} cos(theta_j);  Z_w = prod_{j=0..w} cos(theta_j)
__device__ __forceinline__ void proj_compute(const void* x, const void* phi,
                                             bool f32, int m, float* z) {
    int h = m & (HH - 1);
    float th[DKW];
    if (f32) {
        const float4* xp = (const float4*)((const float*)x + (size_t)m * DKW);
        const float4* pp = (const float4*)((const float*)phi + h * DKW);
        float4 x0 = xp[0], x1 = xp[1];
        float4 p0 = pp[0], p1 = pp[1];
        th[0] = x0.x + p0.x; th[1] = x0.y + p0.y; th[2] = x0.z + p0.z; th[3] = x0.w + p0.w;
        th[4] = x1.x + p1.x; th[5] = x1.y + p1.y; th[6] = x1.z + p1.z; th[7] = x1.w + p1.w;
    } else {
        union { uint4 u; bf16 hv[8]; } xu, pu;
        xu.u = *(const uint4*)((const bf16*)x + (size_t)m * DKW);
        pu.u = *(const uint4*)((const bf16*)phi + (size_t)h * DKW);
#pragma unroll
        for (int j = 0; j < DKW; ++j)
            th[j] = __bfloat162float(xu.hv[j]) + __bfloat162float(pu.hv[j]);
    }
    float c[DKW];
#pragma unroll
    for (int j = 0; j < DKW; ++j) c[j] = __cosf(th[j]);
    float suf = c[1];
#pragma unroll
    for (int j = 2; j < DKW; ++j) suf *= c[j];
    z[0] = suf;
    float pre = c[0];
#pragma unroll
    for (int w = 1; w < DKW; ++w) { pre *= c[w]; z[w] = pre; }
}

// Fast path: write fp16 projH [b][s][e] and transposed projT [b][e][s].
__global__ __launch_bounds__(256) void proj_f16_kernel(const void* __restrict__ x,
                                                       const void* __restrict__ phi,
                                                       const int* __restrict__ flag,
                                                       _Float16* __restrict__ projH,
                                                       _Float16* __restrict__ projT) {
    int m = blockIdx.x * blockDim.x + threadIdx.x;  // (b*S + s)*H + h
    float z[DKW];
    proj_compute(x, phi, flag[0] != 0, m, z);

    union { half8v v; _Float16 h[8]; } o;
#pragma unroll
    for (int j = 0; j < DKW; ++j) o.h[j] = (_Float16)z[j];
    *(half8v*)(projH + (size_t)m * DKW) = o.v;

    int h = m & (HH - 1);
    int bs = m >> 3;           // b*S + s
    int b = bs >> 10;
    int s = bs & (SS - 1);
#pragma unroll
    for (int j = 0; j < DKW; ++j)
        projT[((size_t)(b * EE + h * DKW + j)) * SS + s] = o.h[j];
}

// Slow-path (fallback) fp32 projection.
__global__ __launch_bounds__(256) void proj_f32_kernel(const void* __restrict__ x,
                                                       const void* __restrict__ phi,
                                                       const int* __restrict__ flag,
                                                       float* __restrict__ proj) {
    int m = blockIdx.x * blockDim.x + threadIdx.x;
    float z[DKW];
    proj_compute(x, phi, flag[0] != 0, m, z);
    float4* o = (float4*)(proj + (size_t)m * DKW);
    o[0] = make_float4(z[0], z[1], z[2], z[3]);
    o[1] = make_float4(z[4], z[5], z[6], z[7]);
}

// ---------------------------------------------------------------------------
// Scores GEMM: S[b][m][n] = scale * sum_d P[b][m][d] * P[b][n][d], fp16 out.
// Block = 256 thr (4 waves); block tile 64x64; wave = 16-row group x 64 cols.
// MFMA A-layout: A[m=lane&15][k=quad*8+j]; B-layout: B[k=quad*8+j][n=lane&15].
// Both fragments read contiguous 16B rows of projH (B[k][n] = P[n][k]).
__global__ __launch_bounds__(256) void scores_kernel(const _Float16* __restrict__ projH,
                                                     _Float16* __restrict__ Smat) {
    const int b = blockIdx.z;
    const int tid = threadIdx.x;
    const int wave = tid >> 6, lane = tid & 63;
    const int lr = lane & 15, quad = lane >> 4;
    const int m0 = blockIdx.y * 64 + wave * 16;
    const int n0 = blockIdx.x * 64;
    const float scale = 0.35355339059327373f;  // 1/sqrt(DK)

    const _Float16* Pb = projH + (size_t)b * SS * EE;

    half8v a0 = *(const half8v*)(Pb + (m0 + lr) * EE + quad * 8);
    half8v a1 = *(const half8v*)(Pb + (m0 + lr) * EE + 32 + quad * 8);

    _Float16* Sb = Smat + (size_t)b * SS * SS;
#pragma unroll
    for (int c = 0; c < 4; ++c) {
        int n = n0 + c * 16;
        half8v b0 = *(const half8v*)(Pb + (n + lr) * EE + quad * 8);
        half8v b1 = *(const half8v*)(Pb + (n + lr) * EE + 32 + quad * 8);
        floatx4 acc = {0.f, 0.f, 0.f, 0.f};
        acc = MFMA16(a0, b0, acc);
        acc = MFMA16(a1, b1, acc);
        // C/D layout: col = lane&15, row = quad*4 + reg
#pragma unroll
        for (int r = 0; r < 4; ++r)
            Sb[(size_t)(m0 + quad * 4 + r) * SS + n + lr] = (_Float16)(acc[r] * scale);
    }
}

// ---------------------------------------------------------------------------
// Row softmax in place, output pre-scaled by 512 (keeps fp16 away from
// denormal flush in the PV MFMA); PV epilogue divides by 512.
__global__ __launch_bounds__(256) void softmax_kernel(_Float16* __restrict__ Smat) {
    const int row = blockIdx.x;             // b*S + m
    const int tid = threadIdx.x;
    _Float16* Sr = Smat + (size_t)row * SS;

    __shared__ float red[8];
    union { ushort4 u; _Float16 h[4]; } v;
    v.u = *(const ushort4*)(Sr + tid * 4);
    float f[4];
#pragma unroll
    for (int i = 0; i < 4; ++i) f[i] = (float)v.h[i];

    float mloc = fmaxf(fmaxf(f[0], f[1]), fmaxf(f[2], f[3]));
#pragma unroll
    for (int off = 32; off > 0; off >>= 1)
        mloc = fmaxf(mloc, __shfl_xor(mloc, off, 64));
    if ((tid & 63) == 0) red[tid >> 6] = mloc;
    __syncthreads();
    float mx = fmaxf(fmaxf(red[0], red[1]), fmaxf(red[2], red[3]));

    float e[4], lsum = 0.f;
#pragma unroll
    for (int i = 0; i < 4; ++i) { e[i] = __expf(f[i] - mx); lsum += e[i]; }
#pragma unroll
    for (int off = 32; off > 0; off >>= 1)
        lsum += __shfl_xor(lsum, off, 64);
    if ((tid & 63) == 0) red[4 + (tid >> 6)] = lsum;
    __syncthreads();
    float inv = 512.f / (red[4] + red[5] + red[6] + red[7]);

#pragma unroll
    for (int i = 0; i < 4; ++i) v.h[i] = (_Float16)(e[i] * inv);
    *(ushort4*)(Sr + tid * 4) = v.u;
}

// ---------------------------------------------------------------------------
// PV GEMM + fused output linear.
// Block = 256 thr; tile = 32 q-rows x 64 cols; wave (rowg = w>>1, colg = w&1)
// owns 16 rows x 32 cols. ctx = (P/512) . V  via MFMA over K=1024, then
// out = ctx @ W^T + bias via LDS round-trip (C-layout -> A-layout).
__global__ __launch_bounds__(256) void pv_kernel(const _Float16* __restrict__ Pmat,
                                                 const _Float16* __restrict__ projT,
                                                 const void* __restrict__ Wp,
                                                 const void* __restrict__ biasp,
                                                 const int* __restrict__ flag,
                                                 void* __restrict__ outp) {
    const int b = blockIdx.y;
    const int tid = threadIdx.x;
    const int wave = tid >> 6, lane = tid & 63;
    const int lr = lane & 15, quad = lane >> 4;
    const int rowg = wave >> 1, colg = wave & 1;
    const int m0 = blockIdx.x * 32 + rowg * 16;    // global query row base
    const bool f32 = (flag[0] != 0);

    const _Float16* Pb = Pmat + ((size_t)b * SS + m0 + lr) * SS;
    const _Float16* VT0 = projT + ((size_t)b * EE + colg * 32 + lr) * SS;
    const _Float16* VT1 = VT0 + 16 * SS;

    floatx4 acc0 = {0.f, 0.f, 0.f, 0.f};
    floatx4 acc1 = {0.f, 0.f, 0.f, 0.f};
#pragma unroll 4
    for (int t = 0; t < SS; t += 32) {
        half8v a  = *(const half8v*)(Pb  + t + quad * 8);
        half8v v0 = *(const half8v*)(VT0 + t + quad * 8);
        half8v v1 = *(const half8v*)(VT1 + t + quad * 8);
        acc0 = MFMA16(a, v0, acc0);
        acc1 = MFMA16(a, v1, acc1);
    }

    // ctx tile -> LDS (fp16), row stride 72 (144B: 16B-aligned rows,
    // conflict-free b128 reads). Undo the 512x P pre-scale here.
    __shared__ _Float16 ctx_lds[32][72];
#pragma unroll
    for (int r = 0; r < 4; ++r) {
        int row_l = rowg * 16 + quad * 4 + r;
        ctx_lds[row_l][colg * 32 + lr]      = (_Float16)(acc0[r] * (1.f / 512.f));
        ctx_lds[row_l][colg * 32 + 16 + lr] = (_Float16)(acc1[r] * (1.f / 512.f));
    }
    __syncthreads();

    // out[m][o] = bias[o] + sum_e ctx[m][e] * W[o][e]; K = 64 -> 2 chunks.
    half8v ca0 = *(const half8v*)(&ctx_lds[rowg * 16 + lr][quad * 8]);
    half8v ca1 = *(const half8v*)(&ctx_lds[rowg * 16 + lr][32 + quad * 8]);

#pragma unroll
    for (int c = 0; c < 2; ++c) {
        int o = colg * 32 + c * 16 + lr;
        half8v wb0, wb1;
        if (f32) {
            const float* wr = (const float*)Wp + o * EE;
            union { half8v v; _Float16 h[8]; } w0, w1;
#pragma unroll
            for (int j = 0; j < 8; ++j) {
                w0.h[j] = (_Float16)wr[quad * 8 + j];
                w1.h[j] = (_Float16)wr[32 + quad * 8 + j];
            }
            wb0 = w0.v; wb1 = w1.v;
        } else {
            const bf16* wr = (const bf16*)Wp + o * EE;
            union { uint4 u; bf16 hv[8]; } r0, r1;
            r0.u = *(const uint4*)(wr + quad * 8);
            r1.u = *(const uint4*)(wr + 32 + quad * 8);
            union { half8v v; _Float16 h[8]; } w0, w1;
#pragma unroll
            for (int j = 0; j < 8; ++j) {
                w0.h[j] = (_Float16)__bfloat162float(r0.hv[j]);
                w1.h[j] = (_Float16)__bfloat162float(r1.hv[j]);
            }
            wb0 = w0.v; wb1 = w1.v;
        }
        floatx4 oacc = {0.f, 0.f, 0.f, 0.f};
        oacc = MFMA16(ca0, wb0, oacc);
        oacc = MFMA16(ca1, wb1, oacc);

        float bo = f32 ? ((const float*)biasp)[o]
                       : __bfloat162float(((const bf16*)biasp)[o]);
#pragma unroll
        for (int r = 0; r < 4; ++r) {
            size_t oi = ((size_t)b * SS + m0 + quad * 4 + r) * EE + o;
            float val = oacc[r] + bo;
            if (f32) ((float*)outp)[oi] = val;
            else     ((bf16*)outp)[oi] = __float2bfloat16(val);
        }
    }
}

// ---------------------------------------------------------------------------
// Fallback (R2-proven) fp32 single-row attention kernel, used if ws is small.
__global__ __launch_bounds__(256) void attn_kernel(const float* __restrict__ proj,
                                                   const void* __restrict__ Wp,
                                                   const void* __restrict__ biasp,
                                                   const int* __restrict__ flag,
                                                   void* __restrict__ outp) {
    const int b = blockIdx.y;
    const int s = blockIdx.x;
    const int tid = threadIdx.x;
    const bool f32 = (flag[0] != 0);

    __shared__ float q[EE];
    __shared__ float p[SS];
    __shared__ float red[8];
    __shared__ float part[4][EE];
    __shared__ float ctx[EE];

    const float* Pb = proj + (size_t)b * SS * EE;
    if (tid < EE) q[tid] = Pb[(size_t)s * EE + tid];
    __syncthreads();

    const float scale = 0.35355339059327373f;
    float sc[4];
    float mloc = -1e30f;
    const float4* qv = (const float4*)q;
#pragma unroll
    for (int k = 0; k < 4; ++k) {
        int t = tid + k * 256;
        const float4* row = (const float4*)(Pb + (size_t)t * EE);
        float dot = 0.f;
#pragma unroll
        for (int i = 0; i < 16; ++i) {
            float4 r = row[i]; float4 qq = qv[i];
            dot += r.x * qq.x + r.y * qq.y + r.z * qq.z + r.w * qq.w;
        }
        sc[k] = dot * scale;
        mloc = fmaxf(mloc, sc[k]);
    }
#pragma unroll
    for (int off = 32; off > 0; off >>= 1)
        mloc = fmaxf(mloc, __shfl_xor(mloc, off, 64));
    int wave = tid >> 6;
    if ((tid & 63) == 0) red[wave] = mloc;
    __syncthreads();
    float m = fmaxf(fmaxf(red[0], red[1]), fmaxf(red[2], red[3]));
    float lsum = 0.f;
#pragma unroll
    for (int k = 0; k < 4; ++k) {
        float e = __expf(sc[k] - m);
        p[tid + k * 256] = e;
        lsum += e;
    }
#pragma unroll
    for (int off = 32; off > 0; off >>= 1)
        lsum += __shfl_xor(lsum, off, 64);
    if ((tid & 63) == 0) red[4 + wave] = lsum;
    __syncthreads();
    float sumv = red[4] + red[5] + red[6] + red[7];

    int e_idx = tid & 63;
    int chunk = tid >> 6;
    float acc = 0.f;
    int t0 = chunk * 256;
    for (int t = t0; t < t0 + 256; ++t)
        acc += p[t] * Pb[(size_t)t * EE + e_idx];
    part[chunk][e_idx] = acc;
    __syncthreads();
    if (tid < EE)
        ctx[tid] = (part[0][tid] + part[1][tid] + part[2][tid] + part[3][tid]) / sumv;
    __syncthreads();

    if (tid < EE) {
        float acc2;
        if (f32) {
            const float* wr = (const float*)Wp + (size_t)tid * EE;
            acc2 = ((const float*)biasp)[tid];
#pragma unroll
            for (int j = 0; j < EE; ++j) acc2 += wr[j] * ctx[j];
        } else {
            const bf16* wr = (const bf16*)Wp + (size_t)tid * EE;
            acc2 = __bfloat162float(((const bf16*)biasp)[tid]);
#pragma unroll
            for (int j = 0; j < EE; ++j) acc2 += __bfloat162float(wr[j]) * ctx[j];
        }
        size_t oi = ((size_t)(b * SS + s)) * EE + tid;
        if (f32) ((float*)outp)[oi] = acc2;
        else     ((bf16*)outp)[oi] = __float2bfloat16(acc2);
    }
}

// ---------------------------------------------------------------------------
extern "C" void kernel_launch(void* const* d_in, const int* in_sizes, int n_in,
                              void* d_out, int out_size, void* d_ws, size_t ws_size,
                              hipStream_t stream) {
    const void* x    = d_in[0];
    const void* phi  = d_in[1];
    const void* W    = d_in[2];
    const void* bias = d_in[3];

    int* flag = (int*)d_ws;
    detect_kernel<<<dim3(1), dim3(256), 0, stream>>>((const u16*)x, flag);

    if (ws_size >= WS_NEED_FAST) {
        _Float16* projH = (_Float16*)((char*)d_ws + OFF_PROJH);
        _Float16* projT = (_Float16*)((char*)d_ws + OFF_PROJT);
        _Float16* Smat  = (_Float16*)((char*)d_ws + OFF_SMAT);

        proj_f16_kernel<<<dim3(BB * SS * HH / 256), dim3(256), 0, stream>>>(
            x, phi, flag, projH, projT);
        scores_kernel<<<dim3(SS / 64, SS / 64, BB), dim3(256), 0, stream>>>(projH, Smat);
        softmax_kernel<<<dim3(BB * SS), dim3(256), 0, stream>>>(Smat);
        pv_kernel<<<dim3(SS / 32, BB), dim3(256), 0, stream>>>(
            Smat, projT, W, bias, flag, d_out);
    } else {
        float* proj = (float*)((char*)d_ws + 256);
        proj_f32_kernel<<<dim3(BB * SS * HH / 256), dim3(256), 0, stream>>>(x, phi, flag, proj);
        dim3 g(SS, BB);
        attn_kernel<<<g, dim3(256), 0, stream>>>(proj, W, bias, flag, d_out);
    }
}

// Round 4
// 85.038 us; speedup vs baseline: 6.5381x; 1.2658x over previous
//
#include <hip/hip_runtime.h>
#include <hip/hip_bf16.h>

// Problem constants (from reference): B=8, S=1024, E=64, H=8, DK=8
#define BB 8
#define SS 1024
#define EE 64
#define HH 8
#define DKW 8

typedef __hip_bfloat16 bf16;
typedef unsigned short u16;
typedef _Float16 half8v __attribute__((ext_vector_type(8)));
typedef float floatx4 __attribute__((ext_vector_type(4)));

#define MFMA16(a, b, c) __builtin_amdgcn_mfma_f32_16x16x32_f16(a, b, c, 0, 0, 0)

// d_ws layout: [0,1MB) projH fp16 [B][S][E]; [1MB,2MB) projT fp16 [B][E][S]
#define OFF_PROJT ((size_t)BB * SS * EE * 2)

// ---------------------------------------------------------------------------
// Block-uniform dtype self-detection: read the first 2048 even-indexed u16s
// of `base`. If the buffer is really float32, those are random f32-mantissa
// bits -> ~48% decode (as bf16) to |v| >= 32; genuine bf16/small data -> ~0.
// Same slice for every block => identical, deterministic result.
template <int NT>
__device__ __forceinline__ bool detect_f32(const u16* __restrict__ base,
                                           int tid, int* red) {
    int cnt = 0;
#pragma unroll
    for (int i = tid; i < 2048; i += NT) {
        u16 u = base[i * 2];
        int ex = (u >> 7) & 0xFF;
        cnt += (ex >= 0x84) ? 1 : 0;
    }
#pragma unroll
    for (int off = 32; off > 0; off >>= 1) cnt += __shfl_xor(cnt, off, 64);
    if ((tid & 63) == 0) red[tid >> 6] = cnt;
    __syncthreads();
    int tot = 0;
#pragma unroll
    for (int w = 0; w < NT / 64; ++w) tot += red[w];
    return tot > 64;
}

// ---------------------------------------------------------------------------
// Analytic quantum projection (R0 derivation, verified R2/R3):
//   Z_0 = prod_{j=1..7} cos(theta_j);  Z_w = prod_{j=0..w} cos(theta_j)
__device__ __forceinline__ void proj_compute(const void* x, const void* phi,
                                             bool f32, int m, float* z) {
    int h = m & (HH - 1);
    float th[DKW];
    if (f32) {
        const float4* xp = (const float4*)((const float*)x + (size_t)m * DKW);
        const float4* pp = (const float4*)((const float*)phi + h * DKW);
        float4 x0 = xp[0], x1 = xp[1];
        float4 p0 = pp[0], p1 = pp[1];
        th[0] = x0.x + p0.x; th[1] = x0.y + p0.y; th[2] = x0.z + p0.z; th[3] = x0.w + p0.w;
        th[4] = x1.x + p1.x; th[5] = x1.y + p1.y; th[6] = x1.z + p1.z; th[7] = x1.w + p1.w;
    } else {
        union { uint4 u; bf16 hv[8]; } xu, pu;
        xu.u = *(const uint4*)((const bf16*)x + (size_t)m * DKW);
        pu.u = *(const uint4*)((const bf16*)phi + (size_t)h * DKW);
#pragma unroll
        for (int j = 0; j < DKW; ++j)
            th[j] = __bfloat162float(xu.hv[j]) + __bfloat162float(pu.hv[j]);
    }
    float c[DKW];
#pragma unroll
    for (int j = 0; j < DKW; ++j) c[j] = __cosf(th[j]);
    float suf = c[1];
#pragma unroll
    for (int j = 2; j < DKW; ++j) suf *= c[j];
    z[0] = suf;
    float pre = c[0];
#pragma unroll
    for (int w = 1; w < DKW; ++w) { pre *= c[w]; z[w] = pre; }
}

// ---------------------------------------------------------------------------
// Projection: fp16 projH [b][s][e] (direct) + projT [b][e][s] via LDS-staged
// transpose (16B coalesced stores). Block = 256 thr = 32 (b,s) pairs.
__global__ __launch_bounds__(256) void proj_f16_kernel(const void* __restrict__ x,
                                                       const void* __restrict__ phi,
                                                       _Float16* __restrict__ projH,
                                                       _Float16* __restrict__ projT) {
    __shared__ int redd[4];
    __shared__ _Float16 zt[EE][40];  // [e][s_local]; stride 40 halves = 80 B (16B-aligned rows)
    const int tid = threadIdx.x;
    const bool f32 = detect_f32<256>((const u16*)x, tid, redd);

    const int m = blockIdx.x * 256 + tid;  // (b*S + s)*H + h
    float z[DKW];
    proj_compute(x, phi, f32, m, z);

    union { half8v v; _Float16 h[8]; } o;
#pragma unroll
    for (int j = 0; j < DKW; ++j) o.h[j] = (_Float16)z[j];
    *(half8v*)(projH + (size_t)m * DKW) = o.v;

    const int h = m & (HH - 1);
    const int sl = (tid >> 3) & 31;  // s_local within the block's 32 s values
#pragma unroll
    for (int j = 0; j < DKW; ++j) zt[h * DKW + j][sl] = o.h[j];
    __syncthreads();

    const int b = blockIdx.x >> 5;             // (blk*32)/1024
    const int s0 = (blockIdx.x * 32) & (SS - 1);
    const int row = tid >> 2, ch = tid & 3;    // 64 rows x 4 chunks of 8 halves
    half8v vv = *(const half8v*)(&zt[row][ch * 8]);
    *(half8v*)(projT + ((size_t)(b * EE + row)) * SS + s0 + ch * 8) = vv;
}

// ---------------------------------------------------------------------------
// Fused attention: per block, 32 query rows x full S=1024.
//   phase 1: S_tile = scale * Q . K^T   (MFMA, fp16 -> LDS)
//   phase 2: exact softmax in LDS (stores 256*exp(s-max), rowsum fp32)
//   phase 3: ctx = P . V (MFMA, A from LDS, B from projT)
//   phase 4: out = ctx @ W^T + bias (MFMA via ctx LDS round-trip)
// 512 threads = 8 waves; grid (S/32, B) = 256 blocks.
#define STRD 1048  // Stile row stride in halves: 4/8-row strides -> 2-way (free) bank overlap
__global__ __launch_bounds__(512) void fused_attn(const _Float16* __restrict__ projH,
                                                  const _Float16* __restrict__ projT,
                                                  const void* __restrict__ Wp,
                                                  const void* __restrict__ biasp,
                                                  void* __restrict__ outp) {
    __shared__ _Float16 Stile[32][STRD];   // 67,072 B
    __shared__ _Float16 ctx_lds[32][72];   // 4,608 B, 144B rows (16B-aligned)
    __shared__ float rowsum[32];
    __shared__ int redd[8];

    const int tid = threadIdx.x;
    const int wave = tid >> 6, lane = tid & 63;
    const int lr = lane & 15, quad = lane >> 4;
    const int b = blockIdx.y;
    const int m0 = blockIdx.x * 32;

    const bool f32 = detect_f32<512>((const u16*)Wp, tid, redd);

    const _Float16* Pb = projH + (size_t)b * SS * EE;
    const float scale = 0.35355339059327373f;  // 1/sqrt(DK)

    // ---- phase 1: scores -> Stile
    {
        const int rowg = wave >> 2, colg = wave & 3;
        const _Float16* arow = Pb + (size_t)(m0 + rowg * 16 + lr) * EE;
        half8v a0 = *(const half8v*)(arow + quad * 8);
        half8v a1 = *(const half8v*)(arow + 32 + quad * 8);
#pragma unroll 4
        for (int c = 0; c < 16; ++c) {
            int n = colg * 256 + c * 16;
            const _Float16* brow = Pb + (size_t)(n + lr) * EE;
            half8v b0 = *(const half8v*)(brow + quad * 8);
            half8v b1 = *(const half8v*)(brow + 32 + quad * 8);
            floatx4 acc = {0.f, 0.f, 0.f, 0.f};
            acc = MFMA16(a0, b0, acc);
            acc = MFMA16(a1, b1, acc);
#pragma unroll
            for (int r = 0; r < 4; ++r)
                Stile[rowg * 16 + quad * 4 + r][n + lr] = (_Float16)(acc[r] * scale);
        }
    }
    __syncthreads();

    // ---- phase 2: softmax. 16 threads/row; thread covers cols i*128+seg*8..+7
    // (seg-contiguous chunks -> 2-way bank overlap only).
    {
        const int row = tid >> 4, seg = tid & 15;
        half8v hv[8];
#pragma unroll
        for (int i = 0; i < 8; ++i)
            hv[i] = *(const half8v*)(&Stile[row][i * 128 + seg * 8]);
        float mloc = -1e30f;
#pragma unroll
        for (int i = 0; i < 8; ++i)
#pragma unroll
            for (int j = 0; j < 8; ++j) mloc = fmaxf(mloc, (float)hv[i][j]);
#pragma unroll
        for (int off = 1; off < 16; off <<= 1)
            mloc = fmaxf(mloc, __shfl_xor(mloc, off, 64));
        float lsum = 0.f;
#pragma unroll
        for (int i = 0; i < 8; ++i) {
#pragma unroll
            for (int j = 0; j < 8; ++j) {
                float e = __expf((float)hv[i][j] - mloc);
                lsum += e;
                hv[i][j] = (_Float16)(e * 256.f);  // prescale: avoid fp16 denormal flush
            }
        }
#pragma unroll
        for (int off = 1; off < 16; off <<= 1)
            lsum += __shfl_xor(lsum, off, 64);
        if (seg == 0) rowsum[row] = lsum;
#pragma unroll
        for (int i = 0; i < 8; ++i)
            *(half8v*)(&Stile[row][i * 128 + seg * 8]) = hv[i];
    }
    __syncthreads();

    // ---- phase 3: ctx = P . V ; two interleaved K-chains per wave
    {
        const int rowg = wave >> 2, cw = wave & 3;
        const _Float16* srow = &Stile[rowg * 16 + lr][0];
        const _Float16* vrow = projT + ((size_t)b * EE + cw * 16 + lr) * SS;
        floatx4 acc0 = {0.f, 0.f, 0.f, 0.f};
        floatx4 acc1 = {0.f, 0.f, 0.f, 0.f};
#pragma unroll 4
        for (int t = 0; t < SS; t += 64) {
            half8v aA = *(const half8v*)(srow + t + quad * 8);
            half8v vA = *(const half8v*)(vrow + t + quad * 8);
            half8v aB = *(const half8v*)(srow + t + 32 + quad * 8);
            half8v vB = *(const half8v*)(vrow + t + 32 + quad * 8);
            acc0 = MFMA16(aA, vA, acc0);
            acc1 = MFMA16(aB, vB, acc1);
        }
#pragma unroll
        for (int r = 0; r < 4; ++r) {
            int row_l = rowg * 16 + quad * 4 + r;
            float inv = 1.0f / (256.0f * rowsum[row_l]);
            ctx_lds[row_l][cw * 16 + lr] = (_Float16)((acc0[r] + acc1[r]) * inv);
        }
    }
    __syncthreads();

    // ---- phase 4: out = ctx @ W^T + bias
    {
        const int rowg = wave >> 2, og = wave & 3;
        const int o = og * 16 + lr;
        half8v ca0 = *(const half8v*)(&ctx_lds[rowg * 16 + lr][quad * 8]);
        half8v ca1 = *(const half8v*)(&ctx_lds[rowg * 16 + lr][32 + quad * 8]);
        half8v wb0, wb1;
        if (f32) {
            const float* wr = (const float*)Wp + (size_t)o * EE;
            union { half8v v; _Float16 h[8]; } w0, w1;
#pragma unroll
            for (int j = 0; j < 8; ++j) {
                w0.h[j] = (_Float16)wr[quad * 8 + j];
                w1.h[j] = (_Float16)wr[32 + quad * 8 + j];
            }
            wb0 = w0.v; wb1 = w1.v;
        } else {
            const bf16* wr = (const bf16*)Wp + (size_t)o * EE;
            union { uint4 u; bf16 hv[8]; } r0, r1;
            r0.u = *(const uint4*)(wr + quad * 8);
            r1.u = *(const uint4*)(wr + 32 + quad * 8);
            union { half8v v; _Float16 h[8]; } w0, w1;
#pragma unroll
            for (int j = 0; j < 8; ++j) {
                w0.h[j] = (_Float16)__bfloat162float(r0.hv[j]);
                w1.h[j] = (_Float16)__bfloat162float(r1.hv[j]);
            }
            wb0 = w0.v; wb1 = w1.v;
        }
        floatx4 oacc = {0.f, 0.f, 0.f, 0.f};
        oacc = MFMA16(ca0, wb0, oacc);
        oacc = MFMA16(ca1, wb1, oacc);

        float bo = f32 ? ((const float*)biasp)[o]
                       : __bfloat162float(((const bf16*)biasp)[o]);
#pragma unroll
        for (int r = 0; r < 4; ++r) {
            size_t oi = ((size_t)b * SS + m0 + rowg * 16 + quad * 4 + r) * EE + o;
            float val = oacc[r] + bo;
            if (f32) ((float*)outp)[oi] = val;
            else     ((bf16*)outp)[oi] = __float2bfloat16(val);
        }
    }
}

// ---------------------------------------------------------------------------
extern "C" void kernel_launch(void* const* d_in, const int* in_sizes, int n_in,
                              void* d_out, int out_size, void* d_ws, size_t ws_size,
                              hipStream_t stream) {
    const void* x    = d_in[0];
    const void* phi  = d_in[1];
    const void* W    = d_in[2];
    const void* bias = d_in[3];

    _Float16* projH = (_Float16*)d_ws;
    _Float16* projT = (_Float16*)((char*)d_ws + OFF_PROJT);

    proj_f16_kernel<<<dim3(BB * SS * HH / 256), dim3(256), 0, stream>>>(x, phi, projH, projT);
    fused_attn<<<dim3(SS / 32, BB), dim3(512), 0, stream>>>(projH, projT, W, bias, d_out);
}

// Round 5
// 83.759 us; speedup vs baseline: 6.6380x; 1.0153x over previous
//
#include <hip/hip_runtime.h>
#include <hip/hip_bf16.h>

// Problem constants (from reference): B=8, S=1024, E=64, H=8, DK=8
#define BB 8
#define SS 1024
#define EE 64
#define HH 8
#define DKW 8

typedef __hip_bfloat16 bf16;
typedef unsigned short u16;
typedef _Float16 half8v __attribute__((ext_vector_type(8)));
typedef float floatx4 __attribute__((ext_vector_type(4)));

#define MFMA16(a, b, c) __builtin_amdgcn_mfma_f32_16x16x32_f16(a, b, c, 0, 0, 0)

// d_ws layout: [0,1MB) projH fp16 [B][S][E]; [1MB,2MB) projT fp16 [B][E][S]
#define OFF_PROJT ((size_t)BB * SS * EE * 2)

// ---------------------------------------------------------------------------
// Block-uniform dtype self-detection (R4-proven): if `base` really holds
// float32, even-indexed u16s are random f32 mantissa bits -> ~48% decode (as
// bf16) to |v| >= 32; genuine bf16 N(0,1) -> ~0. Deterministic per buffer.
template <int NT>
__device__ __forceinline__ bool detect_f32(const u16* __restrict__ base,
                                           int tid, int* red) {
    int cnt = 0;
#pragma unroll
    for (int i = tid; i < 2048; i += NT) {
        u16 u = base[i * 2];
        int ex = (u >> 7) & 0xFF;
        cnt += (ex >= 0x84) ? 1 : 0;
    }
#pragma unroll
    for (int off = 32; off > 0; off >>= 1) cnt += __shfl_xor(cnt, off, 64);
    if ((tid & 63) == 0) red[tid >> 6] = cnt;
    __syncthreads();
    int tot = 0;
#pragma unroll
    for (int w = 0; w < NT / 64; ++w) tot += red[w];
    return tot > 64;
}

// ---------------------------------------------------------------------------
// Analytic quantum projection (R0 derivation, verified R2-R4):
//   Z_0 = prod_{j=1..7} cos(theta_j);  Z_w = prod_{j=0..w} cos(theta_j)
__device__ __forceinline__ void proj_compute(const void* x, const void* phi,
                                             bool f32, int m, float* z) {
    int h = m & (HH - 1);
    float th[DKW];
    if (f32) {
        const float4* xp = (const float4*)((const float*)x + (size_t)m * DKW);
        const float4* pp = (const float4*)((const float*)phi + h * DKW);
        float4 x0 = xp[0], x1 = xp[1];
        float4 p0 = pp[0], p1 = pp[1];
        th[0] = x0.x + p0.x; th[1] = x0.y + p0.y; th[2] = x0.z + p0.z; th[3] = x0.w + p0.w;
        th[4] = x1.x + p1.x; th[5] = x1.y + p1.y; th[6] = x1.z + p1.z; th[7] = x1.w + p1.w;
    } else {
        union { uint4 u; bf16 hv[8]; } xu, pu;
        xu.u = *(const uint4*)((const bf16*)x + (size_t)m * DKW);
        pu.u = *(const uint4*)((const bf16*)phi + (size_t)h * DKW);
#pragma unroll
        for (int j = 0; j < DKW; ++j)
            th[j] = __bfloat162float(xu.hv[j]) + __bfloat162float(pu.hv[j]);
    }
    float c[DKW];
#pragma unroll
    for (int j = 0; j < DKW; ++j) c[j] = __cosf(th[j]);
    float suf = c[1];
#pragma unroll
    for (int j = 2; j < DKW; ++j) suf *= c[j];
    z[0] = suf;
    float pre = c[0];
#pragma unroll
    for (int w = 1; w < DKW; ++w) { pre *= c[w]; z[w] = pre; }
}

// ---------------------------------------------------------------------------
// Projection: fp16 projH [b][s][e] + projT [b][e][s] via LDS-staged transpose.
__global__ __launch_bounds__(256) void proj_f16_kernel(const void* __restrict__ x,
                                                       const void* __restrict__ phi,
                                                       _Float16* __restrict__ projH,
                                                       _Float16* __restrict__ projT) {
    __shared__ int redd[4];
    __shared__ _Float16 zt[EE][40];
    const int tid = threadIdx.x;
    const bool f32 = detect_f32<256>((const u16*)x, tid, redd);

    const int m = blockIdx.x * 256 + tid;  // (b*S + s)*H + h
    float z[DKW];
    proj_compute(x, phi, f32, m, z);

    union { half8v v; _Float16 h[8]; } o;
#pragma unroll
    for (int j = 0; j < DKW; ++j) o.h[j] = (_Float16)z[j];
    *(half8v*)(projH + (size_t)m * DKW) = o.v;

    const int h = m & (HH - 1);
    const int sl = (tid >> 3) & 31;
#pragma unroll
    for (int j = 0; j < DKW; ++j) zt[h * DKW + j][sl] = o.h[j];
    __syncthreads();

    const int b = blockIdx.x >> 5;
    const int s0 = (blockIdx.x * 32) & (SS - 1);
    const int row = tid >> 2, ch = tid & 3;
    half8v vv = *(const half8v*)(&zt[row][ch * 8]);
    *(half8v*)(projT + ((size_t)(b * EE + row)) * SS + s0 + ch * 8) = vv;
}

// ---------------------------------------------------------------------------
// Fused attention: 16 query rows per block, 512 threads (8 waves),
// grid (S/16, B) = 512 blocks -> 2 resident blocks/CU (LDS ~40 KB).
// Stile: flat 16x1024 fp16, XOR-swizzled (stride == 0 mod 32 dwords + blk^row):
// phase-3 b128 A-reads land 2 lanes/bank (free).
__device__ __forceinline__ int sidx(int row, int colblk) {
    // colblk in units of 8 halves (16 B)
    return row * 1024 + ((colblk ^ (row & 7)) << 3);
}

__global__ __launch_bounds__(512) void fused_attn(const _Float16* __restrict__ projH,
                                                  const _Float16* __restrict__ projT,
                                                  const void* __restrict__ Wp,
                                                  const void* __restrict__ biasp,
                                                  void* __restrict__ outp) {
    __shared__ _Float16 Stile[16 * 1024];          // 32 KB, swizzled
    __shared__ float    pacc[4][16][17];           // 4.3 KB K-split partials
    __shared__ _Float16 ctx_lds[16][72];           // 2.3 KB
    __shared__ float    rowsum[16];
    __shared__ int      redd[8];

    const int tid = threadIdx.x;
    const int wave = tid >> 6, lane = tid & 63;
    const int lr = lane & 15, quad = lane >> 4;
    const int b = blockIdx.y;
    const int m0 = blockIdx.x * 16;

    const bool f32 = detect_f32<512>((const u16*)Wp, tid, redd);

    const _Float16* Pb = projH + (size_t)b * SS * EE;
    const float scale = 0.35355339059327373f;  // 1/sqrt(DK)

    // ---- phase 1: S = scale * Q . K^T  -> Stile (each wave: 128 cols)
    {
        const _Float16* arow = Pb + (size_t)(m0 + lr) * EE;
        half8v a0 = *(const half8v*)(arow + quad * 8);
        half8v a1 = *(const half8v*)(arow + 32 + quad * 8);
#pragma unroll 4
        for (int c = 0; c < 8; ++c) {
            int n = wave * 128 + c * 16;
            const _Float16* brow = Pb + (size_t)(n + lr) * EE;
            half8v b0 = *(const half8v*)(brow + quad * 8);
            half8v b1 = *(const half8v*)(brow + 32 + quad * 8);
            floatx4 acc = {0.f, 0.f, 0.f, 0.f};
            acc = MFMA16(a0, b0, acc);
            acc = MFMA16(a1, b1, acc);
#pragma unroll
            for (int r = 0; r < 4; ++r) {
                int row = quad * 4 + r, col = n + lr;
                Stile[sidx(row, col >> 3) + (col & 7)] = (_Float16)(acc[r] * scale);
            }
        }
    }
    __syncthreads();

    // ---- phase 2: exact softmax. 32 threads/row; swizzle is a within-row
    // permutation, so max/sum and write-back are unaffected.
    {
        const int row = tid >> 5, seg = tid & 31;
        half8v hv[4];
#pragma unroll
        for (int i = 0; i < 4; ++i)
            hv[i] = *(const half8v*)(&Stile[sidx(row, i * 32 + seg)]);
        float mloc = -1e30f;
#pragma unroll
        for (int i = 0; i < 4; ++i)
#pragma unroll
            for (int j = 0; j < 8; ++j) mloc = fmaxf(mloc, (float)hv[i][j]);
#pragma unroll
        for (int off = 16; off > 0; off >>= 1)
            mloc = fmaxf(mloc, __shfl_xor(mloc, off, 64));
        float lsum = 0.f;
#pragma unroll
        for (int i = 0; i < 4; ++i) {
#pragma unroll
            for (int j = 0; j < 8; ++j) {
                float e = __expf((float)hv[i][j] - mloc);
                lsum += e;
                hv[i][j] = (_Float16)(e * 256.f);  // prescale vs fp16 denormals
            }
        }
#pragma unroll
        for (int off = 16; off > 0; off >>= 1)
            lsum += __shfl_xor(lsum, off, 64);
        if (seg == 0) rowsum[row] = lsum;
#pragma unroll
        for (int i = 0; i < 4; ++i)
            *(half8v*)(&Stile[sidx(row, i * 32 + seg)]) = hv[i];
    }
    __syncthreads();

    // ---- phase 3: ctx = P . V. Wave = (khalf = w>>2) x (colg = w&3);
    // each wave does K=512 for 16 E-cols; khalf-pairs reduce via pacc.
    const int khalf = wave >> 2, colg = wave & 3;
    floatx4 accT;
    {
        const _Float16* vrow = projT + ((size_t)(b * EE + colg * 16 + lr)) * SS
                               + khalf * 512;
        const int sbase = khalf * 64;  // col-block base for this K-half
        floatx4 acc0 = {0.f, 0.f, 0.f, 0.f};
        floatx4 acc1 = {0.f, 0.f, 0.f, 0.f};
#pragma unroll 4
        for (int t = 0; t < 512; t += 64) {
            half8v aA = *(const half8v*)(&Stile[sidx(lr, sbase + (t >> 3) + quad)]);
            half8v vA = *(const half8v*)(vrow + t + quad * 8);
            half8v aB = *(const half8v*)(&Stile[sidx(lr, sbase + ((t + 32) >> 3) + quad)]);
            half8v vB = *(const half8v*)(vrow + t + 32 + quad * 8);
            acc0 = MFMA16(aA, vA, acc0);
            acc1 = MFMA16(aB, vB, acc1);
        }
        accT = acc0 + acc1;
    }
    if (khalf == 1) {
#pragma unroll
        for (int r = 0; r < 4; ++r) pacc[colg][quad * 4 + r][lr] = accT[r];
    }
    __syncthreads();
    if (khalf == 0) {
#pragma unroll
        for (int r = 0; r < 4; ++r) {
            int row_l = quad * 4 + r;
            float inv = 1.0f / (256.0f * rowsum[row_l]);
            ctx_lds[row_l][colg * 16 + lr] =
                (_Float16)((accT[r] + pacc[colg][row_l][lr]) * inv);
        }
    }
    __syncthreads();

    // ---- phase 4: out = ctx @ W^T + bias (waves 0-3)
    if (wave < 4) {
        const int o = wave * 16 + lr;
        half8v ca0 = *(const half8v*)(&ctx_lds[lr][quad * 8]);
        half8v ca1 = *(const half8v*)(&ctx_lds[lr][32 + quad * 8]);
        half8v wb0, wb1;
        if (f32) {
            const float* wr = (const float*)Wp + (size_t)o * EE;
            union { half8v v; _Float16 h[8]; } w0, w1;
#pragma unroll
            for (int j = 0; j < 8; ++j) {
                w0.h[j] = (_Float16)wr[quad * 8 + j];
                w1.h[j] = (_Float16)wr[32 + quad * 8 + j];
            }
            wb0 = w0.v; wb1 = w1.v;
        } else {
            const bf16* wr = (const bf16*)Wp + (size_t)o * EE;
            union { uint4 u; bf16 hv[8]; } r0, r1;
            r0.u = *(const uint4*)(wr + quad * 8);
            r1.u = *(const uint4*)(wr + 32 + quad * 8);
            union { half8v v; _Float16 h[8]; } w0, w1;
#pragma unroll
            for (int j = 0; j < 8; ++j) {
                w0.h[j] = (_Float16)__bfloat162float(r0.hv[j]);
                w1.h[j] = (_Float16)__bfloat162float(r1.hv[j]);
            }
            wb0 = w0.v; wb1 = w1.v;
        }
        floatx4 oacc = {0.f, 0.f, 0.f, 0.f};
        oacc = MFMA16(ca0, wb0, oacc);
        oacc = MFMA16(ca1, wb1, oacc);

        float bo = f32 ? ((const float*)biasp)[o]
                       : __bfloat162float(((const bf16*)biasp)[o]);
#pragma unroll
        for (int r = 0; r < 4; ++r) {
            size_t oi = ((size_t)b * SS + m0 + quad * 4 + r) * EE + o;
            float val = oacc[r] + bo;
            if (f32) ((float*)outp)[oi] = val;
            else     ((bf16*)outp)[oi] = __float2bfloat16(val);
        }
    }
}

// ---------------------------------------------------------------------------
extern "C" void kernel_launch(void* const* d_in, const int* in_sizes, int n_in,
                              void* d_out, int out_size, void* d_ws, size_t ws_size,
                              hipStream_t stream) {
    const void* x    = d_in[0];
    const void* phi  = d_in[1];
    const void* W    = d_in[2];
    const void* bias = d_in[3];

    _Float16* projH = (_Float16*)d_ws;
    _Float16* projT = (_Float16*)((char*)d_ws + OFF_PROJT);

    proj_f16_kernel<<<dim3(BB * SS * HH / 256), dim3(256), 0, stream>>>(x, phi, projH, projT);
    fused_attn<<<dim3(SS / 16, BB), dim3(512), 0, stream>>>(projH, projT, W, bias, d_out);
}